// Round 1
// baseline (7153.503 us; speedup 1.0000x reference)
//
#include <hip/hip_runtime.h>
#include <stdint.h>

typedef unsigned short u16;
typedef unsigned long long u64;
typedef __attribute__((ext_vector_type(8))) short short8;
typedef __attribute__((ext_vector_type(4))) float floatx4;

#define K_IN    4096   // INPUT_SIZE
#define HID     1024   // HIDDEN
#define G4H     4096   // 4*HIDDEN
#define T_STEPS 2048   // WINDOW
#define NWG     128    // scan workgroups; each owns 8 hidden units (1 per wave)
#define SPIN_MAX 60000 // watchdog sweeps; then thread runs free (wrong > hung)

__device__ __forceinline__ u16 f2bf(float f) {
  union { float f; unsigned int i; } v; v.f = f;
  unsigned int lsb = (v.i >> 16) & 1u;
  v.i += 0x7fffu + lsb;
  return (u16)(v.i >> 16);
}
// NaN/Inf -> 0 via INTEGER exponent test: immune to fast-math folding.
__device__ __forceinline__ float finz(float x) {
  unsigned b = __float_as_uint(x);
  return ((b & 0x7f800000u) == 0x7f800000u) ? 0.f : x;
}
__device__ __forceinline__ float sigm(float x) {
  x = fminf(30.f, fmaxf(-30.f, finz(x)));
  return 1.0f / (1.0f + __expf(-x));
}
__device__ __forceinline__ float tanh_s(float x) {
  x = fminf(15.f, fmaxf(-15.f, finz(x)));
  float e = __expf(2.0f * x);
  return (e - 1.0f) / (e + 1.0f);
}

// tagged publish: slot s entry = ((s+1)<<32) | f32bits(h). poison 0xAAAAAAAA never matches.
__device__ __forceinline__ void publish_h(u64* hx, int slot, int idx, float h) {
  h = finz(h);
  u64 v = ((u64)(unsigned)(slot + 1) << 32) | (u64)__float_as_uint(h);
  __hip_atomic_store(&hx[(size_t)slot * HID + idx], v,
                     __ATOMIC_RELAXED, __HIP_MEMORY_SCOPE_AGENT);
}

// poll 2 consecutive entries of slot for tag (slot+1); watchdog -> dead thread
__device__ __forceinline__ void poll2(const u64* hx, int slot, int j0,
                                      float* v, int* alive) {
  const u64* p = hx + (size_t)slot * HID + j0;
  const unsigned tag = (unsigned)(slot + 1);
  if (*alive) {
    int spins = 0;
    for (;;) {
      u64 a = __hip_atomic_load(&p[0], __ATOMIC_RELAXED, __HIP_MEMORY_SCOPE_AGENT);
      u64 b = __hip_atomic_load(&p[1], __ATOMIC_RELAXED, __HIP_MEMORY_SCOPE_AGENT);
      if ((unsigned)(a >> 32) == tag && (unsigned)(b >> 32) == tag) {
        v[0] = finz(__uint_as_float((unsigned)a));
        v[1] = finz(__uint_as_float((unsigned)b));
        return;
      }
      if (++spins > SPIN_MAX) { *alive = 0; break; }
      __builtin_amdgcn_s_sleep(1);
    }
  }
  v[0] = v[1] = 0.f;
}

// broadcast lane 63's value to all lanes (uniform)
__device__ __forceinline__ float bcast63(float x) {
  int i = __builtin_amdgcn_readlane(__builtin_bit_cast(int, x), 63);
  return __builtin_bit_cast(float, i);
}

// ---------------------------------------------------------------------------
// Phase 0: f32 -> bf16 conversion
// ---------------------------------------------------------------------------
__global__ __launch_bounds__(256) void cvt_bf16_k(const float* __restrict__ src,
                                                  u16* __restrict__ dst, int n4) {
  int i = blockIdx.x * 256 + threadIdx.x;
  if (i < n4) {
    float4 v = *(const float4*)(src + (size_t)i * 4);
    u16 o0 = f2bf(v.x), o1 = f2bf(v.y), o2 = f2bf(v.z), o3 = f2bf(v.w);
    ushort4 o = {o0, o1, o2, o3};
    *(ushort4*)(dst + (size_t)i * 4) = o;
  }
}

// ---------------------------------------------------------------------------
// Phase 1: xg = inp @ W_ih^T + b_ih (f32 out). 128x128 tile, BK=64, bf16 MFMA.
// ---------------------------------------------------------------------------
__global__ __launch_bounds__(256) void xg_gemm_k(const u16* __restrict__ A,      // [2048,4096] bf16
                                                 const u16* __restrict__ B,      // [4096,4096] bf16
                                                 const float* __restrict__ bias, // [4096] f32
                                                 float* __restrict__ C)          // [2048,4096] f32
{
  __shared__ __align__(16) u16 As[128 * 64];
  __shared__ __align__(16) u16 Bs[128 * 64];
  const int tid  = threadIdx.x;
  const int lane = tid & 63;
  const int quad = lane >> 4;
  const int l16  = lane & 15;
  const int wid  = tid >> 6;
  const int wm   = wid >> 1, wn = wid & 1;
  const int tileM = blockIdx.y * 128;
  const int tileN = blockIdx.x * 128;

  floatx4 acc[4][4];
  #pragma unroll
  for (int mi = 0; mi < 4; ++mi)
    #pragma unroll
    for (int ni = 0; ni < 4; ++ni)
      acc[mi][ni] = (floatx4){0.f, 0.f, 0.f, 0.f};

  for (int k0 = 0; k0 < K_IN; k0 += 64) {
    #pragma unroll
    for (int i = 0; i < 4; ++i) {
      int c = i * 256 + tid;
      int row = c >> 3, col = (c & 7) * 8;
      *(short8*)(As + c * 8) = *(const short8*)(A + (size_t)(tileM + row) * K_IN + k0 + col);
      *(short8*)(Bs + c * 8) = *(const short8*)(B + (size_t)(tileN + row) * K_IN + k0 + col);
    }
    __syncthreads();
    #pragma unroll
    for (int kk = 0; kk < 64; kk += 32) {
      short8 av[4], bv[4];
      #pragma unroll
      for (int mi = 0; mi < 4; ++mi)
        av[mi] = *(const short8*)(As + (wm * 64 + mi * 16 + l16) * 64 + kk + quad * 8);
      #pragma unroll
      for (int ni = 0; ni < 4; ++ni)
        bv[ni] = *(const short8*)(Bs + (wn * 64 + ni * 16 + l16) * 64 + kk + quad * 8);
      #pragma unroll
      for (int mi = 0; mi < 4; ++mi)
        #pragma unroll
        for (int ni = 0; ni < 4; ++ni)
          acc[mi][ni] = __builtin_amdgcn_mfma_f32_16x16x32_bf16(av[mi], bv[ni], acc[mi][ni], 0, 0, 0);
    }
    __syncthreads();
  }
  #pragma unroll
  for (int ni = 0; ni < 4; ++ni) {
    int n = tileN + wn * 64 + ni * 16 + l16;
    float bn = bias[n];
    #pragma unroll
    for (int mi = 0; mi < 4; ++mi) {
      int mbase = tileM + wm * 64 + mi * 16 + quad * 4;
      #pragma unroll
      for (int r = 0; r < 4; ++r)
        C[(size_t)(mbase + r) * G4H + n] = acc[mi][ni][r] + bn;
    }
  }
}

// ---------------------------------------------------------------------------
// Phase 2: persistent scan, one unit per WAVE (8 waves = 8 units per WG).
// Wave w of block g owns unit u = g*8+w and computes all 4 gate rows of u:
//   - h staged to LDS double-buffer (t&1) -> ONE barrier per step
//   - 4x ds_read_b128 per wave for h; 64 fma/lane
//   - DPP reduction (VALU) instead of shfl_xor butterfly (no LDS-pipe traffic)
//   - gates + c_state computed wave-uniformly after readlane(63); lane 0 publishes
// ---------------------------------------------------------------------------
__global__ __launch_bounds__(512, 1) void lstm_scan_k(const float* __restrict__ Whh,
                                                      const float* __restrict__ bhh,
                                                      const float* __restrict__ h1,
                                                      const float* __restrict__ c1,
                                                      const float* __restrict__ fcw,
                                                      const float* __restrict__ fcb,
                                                      const float* __restrict__ xg,
                                                      u64* hx,        // [T_STEPS+1][1024]
                                                      float* out)     // [2080] f32
{
  const int g    = blockIdx.x;
  const int tid  = threadIdx.x;
  const int lane = tid & 63;
  const int w    = tid >> 6;           // wave 0..7
  const int u    = g * 8 + w;          // hidden unit owned by this wave

  __shared__ __align__(16) float hb[2][HID];   // double-buffered h
  __shared__ float pp[32][16];

  // W_hh rows {u, H+u, 2H+u, 3H+u} -> VGPRs, laid out for float4 LDS reads:
  // wreg[i][j][k] multiplies h[j*256 + lane*4 + k]
  floatx4 wreg[4][4];
  #pragma unroll
  for (int i = 0; i < 4; ++i) {
    const float* wr = Whh + (size_t)(i * HID + u) * HID;
    #pragma unroll
    for (int j = 0; j < 4; ++j)
      wreg[i][j] = *(const floatx4*)(wr + j * 256 + lane * 4);
  }
  const float bh0 = bhh[u], bh1 = bhh[HID + u], bh2 = bhh[2 * HID + u], bh3 = bhh[3 * HID + u];

  float c_state = c1[u];               // wave-uniform
  if (lane == 0) publish_h(hx, 0, u, h1[u]);

  int alive = 1;
  const int j0 = tid * 2;              // 512 threads x 2 entries = 1024
  for (int t = 0; t < T_STEPS; ++t) {
    // prefetch this wave's xg gate values (wave-uniform addresses; hidden under poll)
    const float* xgt = xg + (size_t)t * G4H;
    float xv0 = xgt[u], xv1 = xgt[HID + u], xv2 = xgt[2 * HID + u], xv3 = xgt[3 * HID + u];

    float v[2];
    poll2(hx, t, j0, v, &alive);
    float* hl = hb[t & 1];
    hl[j0 + 0] = v[0]; hl[j0 + 1] = v[1];
    __syncthreads();

    // 4 row-dots per wave via float4 LDS reads (conflict-free, contiguous)
    float s0 = 0.f, s1 = 0.f, s2 = 0.f, s3 = 0.f;
    #pragma unroll
    for (int j = 0; j < 4; ++j) {
      floatx4 hv = *(const floatx4*)(hl + j * 256 + lane * 4);
      #pragma unroll
      for (int k = 0; k < 4; ++k) {
        s0 = fmaf(wreg[0][j][k], hv[k], s0);
        s1 = fmaf(wreg[1][j][k], hv[k], s1);
        s2 = fmaf(wreg[2][j][k], hv[k], s2);
        s3 = fmaf(wreg[3][j][k], hv[k], s3);
      }
    }

    // full-wave DPP reduction (rocPRIM sequence); totals land in lane 63.
    // Level-by-level across the 4 sums so the dependent chains interleave.
#define DPP_LEVEL(mods) \
    asm("v_add_f32 %0, %0, %0 " mods : "+v"(s0)); \
    asm("v_add_f32 %0, %0, %0 " mods : "+v"(s1)); \
    asm("v_add_f32 %0, %0, %0 " mods : "+v"(s2)); \
    asm("v_add_f32 %0, %0, %0 " mods : "+v"(s3));
    DPP_LEVEL("row_shr:1 bound_ctrl:0")
    DPP_LEVEL("row_shr:2 bound_ctrl:0")
    DPP_LEVEL("row_shr:4 bank_mask:0xe")
    DPP_LEVEL("row_shr:8 bank_mask:0xc")
    DPP_LEVEL("row_bcast:15 row_mask:0xa")
    DPP_LEVEL("row_bcast:31 row_mask:0xc")
#undef DPP_LEVEL

    // broadcast totals; gate math is wave-uniform (1 instr per op for all lanes)
    float gi = bcast63(s0) + xv0 + bh0;
    float gf = bcast63(s1) + xv1 + bh1;
    float gg = bcast63(s2) + xv2 + bh2;
    float go = bcast63(s3) + xv3 + bh3;
    float iv = sigm(gi), fv = sigm(gf), gv = tanh_s(gg), ov = sigm(go);
    c_state = finz(fv * c_state + iv * gv);
    float hval = ov * tanh_s(c_state);
    if (lane == 0) {
      publish_h(hx, t + 1, u, hval);
      if (t == 1023) {                 // hs[STRIDE-1], cs[STRIDE-1]
        out[32 + u]       = finz(hval);
        out[32 + HID + u] = finz(c_state);
      }
    }
    // NOTE: no second barrier needed. Next iteration writes hb[(t+1)&1]; a WG
    // can only reach writes of hb[t&1] again (iteration t+2) after every wave
    // device-wide published step t+1, which requires all reads of hb[t&1] done.
  }

  // out[0:32] = tanh(h_fin @ fc_w^T + fc_b): block 0 only
  if (g == 0) {
    float v[2];
    poll2(hx, T_STEPS, j0, v, &alive);
    float* hl = hb[0];
    hl[j0 + 0] = v[0]; hl[j0 + 1] = v[1];
    __syncthreads();
    const int m = tid >> 4, seg = tid & 15;   // 32 rows x 16 partials of 64
    float pacc = 0.f;
    for (int k = seg * 64; k < seg * 64 + 64; ++k)
      pacc = fmaf(fcw[m * HID + k], hl[k], pacc);
    pp[m][seg] = finz(pacc);
    __syncthreads();
    if (tid < 32) {
      float sum = fcb[tid];
      #pragma unroll
      for (int i = 0; i < 16; ++i) sum += pp[tid][i];
      out[tid] = tanh_s(finz(sum));
    }
  }
}

extern "C" void kernel_launch(void* const* d_in, const int* in_sizes, int n_in,
                              void* d_out, int out_size, void* d_ws, size_t ws_size,
                              hipStream_t stream) {
  const float* inp = (const float*)d_in[0];
  const float* h1  = (const float*)d_in[1];
  const float* c1  = (const float*)d_in[2];
  const float* Wih = (const float*)d_in[3];
  const float* Whh = (const float*)d_in[4];
  const float* bih = (const float*)d_in[5];
  const float* bhh = (const float*)d_in[6];
  const float* fcw = (const float*)d_in[7];
  const float* fcb = (const float*)d_in[8];
  float* out = (float*)d_out;

  const size_t xg_bytes  = (size_t)T_STEPS * G4H * 4;             // 33.5 MB
  const size_t hx_bytes  = (size_t)(T_STEPS + 1) * HID * 8;       // 16.8 MB
  const size_t ab_bytes  = (size_t)T_STEPS * K_IN * 2;            // 16.8 MB
  const size_t wb_bytes  = (size_t)G4H * K_IN * 2;                // 33.5 MB
  if (ws_size < xg_bytes + hx_bytes + ab_bytes + wb_bytes) return;

  float* xg   = (float*)d_ws;
  u64*   hx   = (u64*)((char*)d_ws + xg_bytes);
  u16*   Abf  = (u16*)((char*)d_ws + xg_bytes + hx_bytes);
  u16*   Wbf  = (u16*)((char*)d_ws + xg_bytes + hx_bytes + ab_bytes);

  const int nA4 = T_STEPS * K_IN / 4;
  const int nW4 = G4H * K_IN / 4;
  cvt_bf16_k<<<dim3((nA4 + 255) / 256), 256, 0, stream>>>(inp, Abf, nA4);
  cvt_bf16_k<<<dim3((nW4 + 255) / 256), 256, 0, stream>>>(Wih, Wbf, nW4);
  xg_gemm_k<<<dim3(G4H / 128, T_STEPS / 128), 256, 0, stream>>>(Abf, Wbf, bih, xg);
  lstm_scan_k<<<dim3(NWG), 512, 0, stream>>>(Whh, bhh, h1, c1, fcw, fcb, xg, hx, out);
}

// Round 2
// 5171.202 us; speedup vs baseline: 1.3833x; 1.3833x over previous
//
#include <hip/hip_runtime.h>
#include <stdint.h>

typedef unsigned short u16;
typedef unsigned long long u64;
typedef __attribute__((ext_vector_type(8))) short short8;
typedef __attribute__((ext_vector_type(4))) float floatx4;

#define K_IN    4096   // INPUT_SIZE
#define HID     1024   // HIDDEN
#define G4H     4096   // 4*HIDDEN
#define T_STEPS 2048   // WINDOW
#define NWG     128    // scan workgroups; each owns 8 hidden units
#define SPIN_MAX 60000 // watchdog sweeps; then thread runs free (wrong > hung)

__device__ __forceinline__ u16 f2bf(float f) {
  union { float f; unsigned int i; } v; v.f = f;
  unsigned int lsb = (v.i >> 16) & 1u;
  v.i += 0x7fffu + lsb;
  return (u16)(v.i >> 16);
}
// NaN/Inf -> 0 via INTEGER exponent test: immune to fast-math folding.
__device__ __forceinline__ float finz(float x) {
  unsigned b = __float_as_uint(x);
  return ((b & 0x7f800000u) == 0x7f800000u) ? 0.f : x;
}
__device__ __forceinline__ float sigm(float x) {
  x = fminf(30.f, fmaxf(-30.f, finz(x)));
  return 1.0f / (1.0f + __expf(-x));
}
__device__ __forceinline__ float tanh_s(float x) {
  x = fminf(15.f, fmaxf(-15.f, finz(x)));
  float e = __expf(2.0f * x);
  return (e - 1.0f) / (e + 1.0f);
}

// tagged publish: slot s entry = ((s+1)<<32) | f32bits(h). poison 0xAAAAAAAA never matches.
__device__ __forceinline__ void publish_h(u64* hx, int slot, int idx, float h) {
  h = finz(h);
  u64 v = ((u64)(unsigned)(slot + 1) << 32) | (u64)__float_as_uint(h);
  __hip_atomic_store(&hx[(size_t)slot * HID + idx], v,
                     __ATOMIC_RELAXED, __HIP_MEMORY_SCOPE_AGENT);
}

#define HXLD(addr) __hip_atomic_load((addr), __ATOMIC_RELAXED, __HIP_MEMORY_SCOPE_AGENT)

// poll 2 consecutive entries of slot for tag (slot+1); watchdog -> dead thread.
// Software-pipelined depth 3: keep 3 load-pairs in flight, check the oldest.
// Cuts detection quantization vs serial load->check->sleep sweeps (latency-bound).
__device__ __forceinline__ void poll2(const u64* hx, int slot, int j0,
                                      float* v, int* alive) {
  const u64* p = hx + (size_t)slot * HID + j0;
  const unsigned tag = (unsigned)(slot + 1);
  if (*alive) {
    u64 a0 = HXLD(&p[0]), b0 = HXLD(&p[1]);
    u64 a1 = HXLD(&p[0]), b1 = HXLD(&p[1]);
    int spins = 0;
    for (;;) {
      u64 a2 = HXLD(&p[0]), b2 = HXLD(&p[1]);   // issue fresh pair first
      if ((unsigned)(a0 >> 32) == tag && (unsigned)(b0 >> 32) == tag) {
        v[0] = finz(__uint_as_float((unsigned)a0));
        v[1] = finz(__uint_as_float((unsigned)b0));
        return;
      }
      a0 = a1; b0 = b1; a1 = a2; b1 = b2;
      if (++spins > SPIN_MAX) { *alive = 0; break; }
    }
  }
  v[0] = v[1] = 0.f;
}

// ---------------------------------------------------------------------------
// Phase 0: f32 -> bf16 conversion
// ---------------------------------------------------------------------------
__global__ __launch_bounds__(256) void cvt_bf16_k(const float* __restrict__ src,
                                                  u16* __restrict__ dst, int n4) {
  int i = blockIdx.x * 256 + threadIdx.x;
  if (i < n4) {
    float4 v = *(const float4*)(src + (size_t)i * 4);
    u16 o0 = f2bf(v.x), o1 = f2bf(v.y), o2 = f2bf(v.z), o3 = f2bf(v.w);
    ushort4 o = {o0, o1, o2, o3};
    *(ushort4*)(dst + (size_t)i * 4) = o;
  }
}

// ---------------------------------------------------------------------------
// Phase 1: xg = inp @ W_ih^T + b_ih (f32 out). 128x128 tile, BK=64, bf16 MFMA.
// ---------------------------------------------------------------------------
__global__ __launch_bounds__(256) void xg_gemm_k(const u16* __restrict__ A,      // [2048,4096] bf16
                                                 const u16* __restrict__ B,      // [4096,4096] bf16
                                                 const float* __restrict__ bias, // [4096] f32
                                                 float* __restrict__ C)          // [2048,4096] f32
{
  __shared__ __align__(16) u16 As[128 * 64];
  __shared__ __align__(16) u16 Bs[128 * 64];
  const int tid  = threadIdx.x;
  const int lane = tid & 63;
  const int quad = lane >> 4;
  const int l16  = lane & 15;
  const int wid  = tid >> 6;
  const int wm   = wid >> 1, wn = wid & 1;
  const int tileM = blockIdx.y * 128;
  const int tileN = blockIdx.x * 128;

  floatx4 acc[4][4];
  #pragma unroll
  for (int mi = 0; mi < 4; ++mi)
    #pragma unroll
    for (int ni = 0; ni < 4; ++ni)
      acc[mi][ni] = (floatx4){0.f, 0.f, 0.f, 0.f};

  for (int k0 = 0; k0 < K_IN; k0 += 64) {
    #pragma unroll
    for (int i = 0; i < 4; ++i) {
      int c = i * 256 + tid;
      int row = c >> 3, col = (c & 7) * 8;
      *(short8*)(As + c * 8) = *(const short8*)(A + (size_t)(tileM + row) * K_IN + k0 + col);
      *(short8*)(Bs + c * 8) = *(const short8*)(B + (size_t)(tileN + row) * K_IN + k0 + col);
    }
    __syncthreads();
    #pragma unroll
    for (int kk = 0; kk < 64; kk += 32) {
      short8 av[4], bv[4];
      #pragma unroll
      for (int mi = 0; mi < 4; ++mi)
        av[mi] = *(const short8*)(As + (wm * 64 + mi * 16 + l16) * 64 + kk + quad * 8);
      #pragma unroll
      for (int ni = 0; ni < 4; ++ni)
        bv[ni] = *(const short8*)(Bs + (wn * 64 + ni * 16 + l16) * 64 + kk + quad * 8);
      #pragma unroll
      for (int mi = 0; mi < 4; ++mi)
        #pragma unroll
        for (int ni = 0; ni < 4; ++ni)
          acc[mi][ni] = __builtin_amdgcn_mfma_f32_16x16x32_bf16(av[mi], bv[ni], acc[mi][ni], 0, 0, 0);
    }
    __syncthreads();
  }
  #pragma unroll
  for (int ni = 0; ni < 4; ++ni) {
    int n = tileN + wn * 64 + ni * 16 + l16;
    float bn = bias[n];
    #pragma unroll
    for (int mi = 0; mi < 4; ++mi) {
      int mbase = tileM + wm * 64 + mi * 16 + quad * 4;
      #pragma unroll
      for (int r = 0; r < 4; ++r)
        C[(size_t)(mbase + r) * G4H + n] = acc[mi][ni][r] + bn;
    }
  }
}

// ---------------------------------------------------------------------------
// Phase 2: persistent scan. R0 communication skeleton (proven):
//   512 threads poll 2 entries each -> stage h to LDS -> barrier ->
//   dot -> barrier -> tid<8 gate math + ONE coalesced publish (64B store).
// R2 surgical changes (publish pattern untouched):
//   - poll2 pipelined depth-3, no s_sleep (halves detection quantization)
//   - one unit per WAVE for the dot: 4x ds_read_b128 + 64 fma + DPP reduce
//     (VALU pipe) instead of 16x ds_read_b32 + shfl_xor butterfly (LDS pipe)
//     + gsum 32-float round trip. Lane 63 writes 4 sums to gsum2.
// ---------------------------------------------------------------------------
__global__ __launch_bounds__(512, 1) void lstm_scan_k(const float* __restrict__ Whh,
                                                      const float* __restrict__ bhh,
                                                      const float* __restrict__ h1,
                                                      const float* __restrict__ c1,
                                                      const float* __restrict__ fcw,
                                                      const float* __restrict__ fcb,
                                                      const float* __restrict__ xg,
                                                      u64* hx,        // [T_STEPS+1][1024]
                                                      float* out)     // [2080] f32
{
  const int g    = blockIdx.x;
  const int tid  = threadIdx.x;
  const int lane = tid & 63;
  const int w    = tid >> 6;           // wave 0..7
  const int u    = g * 8 + w;          // hidden unit owned by this wave (dot phase)

  __shared__ __align__(16) float h_local[HID];
  __shared__ float gsum2[32];          // [w*4 + q]
  __shared__ float xgb[2][32];         // parity double-buffer, [q*8 + unit]
  __shared__ float bhhb[32];           // [q*8 + unit]
  __shared__ float pp[32][16];

  // W_hh rows {u, H+u, 2H+u, 3H+u} -> VGPRs, laid out for float4 LDS reads:
  // wreg[q][j][k] multiplies h[j*256 + lane*4 + k]
  floatx4 wreg[4][4];
  #pragma unroll
  for (int q = 0; q < 4; ++q) {
    const float* wr = Whh + (size_t)(q * HID + u) * HID;
    #pragma unroll
    for (int j = 0; j < 4; ++j)
      wreg[q][j] = *(const floatx4*)(wr + j * 256 + lane * 4);
  }
  if (tid < 32) bhhb[tid] = bhh[(tid >> 3) * HID + g * 8 + (tid & 7)];

  float c_state = 0.f;
  if (tid < 8) {
    c_state = c1[g * 8 + tid];
    publish_h(hx, 0, g * 8 + tid, h1[g * 8 + tid]);
  }

  int alive = 1;
  const int j0 = tid * 2;              // 512 threads x 2 entries = 1024
  for (int t = 0; t < T_STEPS; ++t) {
    float xval = 0.f;                  // issue xg load before polling
    if (tid < 32) xval = finz(xg[(size_t)t * G4H + (tid >> 3) * HID + g * 8 + (tid & 7)]);
    float v[2];
    poll2(hx, t, j0, v, &alive);
    h_local[j0 + 0] = v[0]; h_local[j0 + 1] = v[1];
    if (tid < 32) xgb[t & 1][tid] = xval;
    __syncthreads();

    // dot: wave w computes the 4 gate rows of unit u via float4 LDS reads
    float s0 = 0.f, s1 = 0.f, s2 = 0.f, s3 = 0.f;
    #pragma unroll
    for (int j = 0; j < 4; ++j) {
      floatx4 hv = *(const floatx4*)(h_local + j * 256 + lane * 4);
      #pragma unroll
      for (int k = 0; k < 4; ++k) {
        s0 = fmaf(wreg[0][j][k], hv[k], s0);
        s1 = fmaf(wreg[1][j][k], hv[k], s1);
        s2 = fmaf(wreg[2][j][k], hv[k], s2);
        s3 = fmaf(wreg[3][j][k], hv[k], s3);
      }
    }

    // full-wave DPP reduction (rocPRIM sequence, proven in R1); totals -> lane 63
#define DPP_LEVEL(mods) \
    asm("v_add_f32 %0, %0, %0 " mods : "+v"(s0)); \
    asm("v_add_f32 %0, %0, %0 " mods : "+v"(s1)); \
    asm("v_add_f32 %0, %0, %0 " mods : "+v"(s2)); \
    asm("v_add_f32 %0, %0, %0 " mods : "+v"(s3));
    DPP_LEVEL("row_shr:1 bound_ctrl:0")
    DPP_LEVEL("row_shr:2 bound_ctrl:0")
    DPP_LEVEL("row_shr:4 bank_mask:0xe")
    DPP_LEVEL("row_shr:8 bank_mask:0xc")
    DPP_LEVEL("row_bcast:15 row_mask:0xa")
    DPP_LEVEL("row_bcast:31 row_mask:0xc")
#undef DPP_LEVEL
    if (lane == 63) {
      gsum2[w * 4 + 0] = s0;
      gsum2[w * 4 + 1] = s1;
      gsum2[w * 4 + 2] = s2;
      gsum2[w * 4 + 3] = s3;
    }
    __syncthreads();

    // gate math + coalesced publish: 8 adjacent threads of wave 0 -> ONE 64B store.
    // Waves 1-7 proceed straight to next iteration's poll (overlap).
    if (tid < 8) {
      const int uu = tid;
      const float* xb = xgb[t & 1];
      float gi = gsum2[uu * 4 + 0] + xb[uu]      + bhhb[uu];
      float gf = gsum2[uu * 4 + 1] + xb[8 + uu]  + bhhb[8 + uu];
      float gg = gsum2[uu * 4 + 2] + xb[16 + uu] + bhhb[16 + uu];
      float go = gsum2[uu * 4 + 3] + xb[24 + uu] + bhhb[24 + uu];
      float iv = sigm(gi), fv = sigm(gf), gv = tanh_s(gg), ov = sigm(go);
      c_state = finz(fv * c_state + iv * gv);
      float hval = ov * tanh_s(c_state);
      publish_h(hx, t + 1, g * 8 + uu, hval);
      if (t == 1023) {                 // hs[STRIDE-1], cs[STRIDE-1]
        out[32 + g * 8 + uu]       = finz(hval);
        out[32 + HID + g * 8 + uu] = finz(c_state);
      }
    }
  }

  // out[0:32] = tanh(h_fin @ fc_w^T + fc_b): block 0 only
  if (g == 0) {
    float v[2];
    poll2(hx, T_STEPS, j0, v, &alive);
    h_local[j0 + 0] = v[0]; h_local[j0 + 1] = v[1];
    __syncthreads();
    const int m = tid >> 4, seg = tid & 15;   // 32 rows x 16 partials of 64
    float pacc = 0.f;
    for (int k = seg * 64; k < seg * 64 + 64; ++k)
      pacc = fmaf(fcw[m * HID + k], h_local[k], pacc);
    pp[m][seg] = finz(pacc);
    __syncthreads();
    if (tid < 32) {
      float sum = fcb[tid];
      #pragma unroll
      for (int i = 0; i < 16; ++i) sum += pp[tid][i];
      out[tid] = tanh_s(finz(sum));
    }
  }
}

extern "C" void kernel_launch(void* const* d_in, const int* in_sizes, int n_in,
                              void* d_out, int out_size, void* d_ws, size_t ws_size,
                              hipStream_t stream) {
  const float* inp = (const float*)d_in[0];
  const float* h1  = (const float*)d_in[1];
  const float* c1  = (const float*)d_in[2];
  const float* Wih = (const float*)d_in[3];
  const float* Whh = (const float*)d_in[4];
  const float* bih = (const float*)d_in[5];
  const float* bhh = (const float*)d_in[6];
  const float* fcw = (const float*)d_in[7];
  const float* fcb = (const float*)d_in[8];
  float* out = (float*)d_out;

  const size_t xg_bytes  = (size_t)T_STEPS * G4H * 4;             // 33.5 MB
  const size_t hx_bytes  = (size_t)(T_STEPS + 1) * HID * 8;       // 16.8 MB
  const size_t ab_bytes  = (size_t)T_STEPS * K_IN * 2;            // 16.8 MB
  const size_t wb_bytes  = (size_t)G4H * K_IN * 2;                // 33.5 MB
  if (ws_size < xg_bytes + hx_bytes + ab_bytes + wb_bytes) return;

  float* xg   = (float*)d_ws;
  u64*   hx   = (u64*)((char*)d_ws + xg_bytes);
  u16*   Abf  = (u16*)((char*)d_ws + xg_bytes + hx_bytes);
  u16*   Wbf  = (u16*)((char*)d_ws + xg_bytes + hx_bytes + ab_bytes);

  const int nA4 = T_STEPS * K_IN / 4;
  const int nW4 = G4H * K_IN / 4;
  cvt_bf16_k<<<dim3((nA4 + 255) / 256), 256, 0, stream>>>(inp, Abf, nA4);
  cvt_bf16_k<<<dim3((nW4 + 255) / 256), 256, 0, stream>>>(Wih, Wbf, nW4);
  xg_gemm_k<<<dim3(G4H / 128, T_STEPS / 128), 256, 0, stream>>>(Abf, Wbf, bih, xg);
  lstm_scan_k<<<dim3(NWG), 512, 0, stream>>>(Whh, bhh, h1, c1, fcw, fcb, xg, hx, out);
}